// Round 1
// baseline (789.893 us; speedup 1.0000x reference)
//
#include <hip/hip_runtime.h>

// MDTA attention, B=8 C=192 H=W=128 heads=4 (ch=48), all-bf16 MFMA pipeline.
// Stages: pack weights -> yT -> q1=W2*yT -> q1T -> q(3x3 as 9 shifted K-segs)
//         -> xT -> kv=W1*xT -> dwconv(k), dwconv(v) -> vT
//         -> rownorms -> Gram(q,k) -> softmax -> PA=proj*attn -> out=PA*vT
// ws layout: KV(96MiB) | R0 | R1 | R2 (48MiB each) | tail(~2MiB). Total ~242MiB.

#define HW 16384

using f32x4  = __attribute__((ext_vector_type(4))) float;
using bf16x8 = __attribute__((ext_vector_type(8))) __bf16;
using u16x8  = __attribute__((ext_vector_type(8))) unsigned short;
typedef unsigned short u16;

__device__ __forceinline__ u16 f2bf(float f) {
  unsigned u = __builtin_bit_cast(unsigned, f);
  u = (u + 0x7fffu + ((u >> 16) & 1u)) >> 16;   // RNE
  return (u16)u;
}
__device__ __forceinline__ float bf2f(u16 s) {
  unsigned u = ((unsigned)s) << 16;
  return __builtin_bit_cast(float, u);
}

// async global->LDS, 16B/lane; LDS dest is wave-uniform base + lane*16
__device__ __forceinline__ void g2l16(const void* g, void* l) {
  __builtin_amdgcn_global_load_lds(
      (const __attribute__((address_space(1))) unsigned int*)g,
      (__attribute__((address_space(3))) unsigned int*)l, 16, 0, 0);
}

// ---------------- weight packing ----------------
// W1[oc][ic] 384x192 ; W2[oc][ic] 192x192 ; W3[oc][seg*192+ic] (seg=dy*3+dx)
__global__ __launch_bounds__(256) void pack_weights(
    const float* __restrict__ kv_w, const float* __restrict__ q_w,
    const float* __restrict__ q_dw_w,
    u16* __restrict__ W1, u16* __restrict__ W2, u16* __restrict__ W3) {
  int i = blockIdx.x * 256 + threadIdx.x;
  if (i < 73728) { W1[i] = f2bf(kv_w[i]); return; }
  i -= 73728;
  if (i < 36864) { W2[i] = f2bf(q_w[i]); return; }
  i -= 36864;
  int oc = i / 1728, r2 = i % 1728;
  int seg = r2 / 192, ic = r2 % 192;
  W3[i] = f2bf(q_dw_w[(oc * 192 + ic) * 9 + seg]);
}

// ---------------- transpose [b][C][HW] -> [b][HW][192] bf16 ----------------
template <typename TIn>
__global__ __launch_bounds__(256) void transpose_kernel(
    const TIn* __restrict__ src, u16* __restrict__ dst, int srcCstride) {
  __shared__ u16 tile[32][34];
  const int bz = blockIdx.z;
  const int n0 = blockIdx.x * 32;
  const int c0 = blockIdx.y * 32;
  const TIn* s = src + (long)bz * srcCstride * HW;
  u16* d = dst + (long)bz * HW * 192;
  const int tx = threadIdx.x & 31;
  const int ty = threadIdx.x >> 5;
#pragma unroll
  for (int i = 0; i < 32; i += 8) {
    if constexpr (sizeof(TIn) == 4)
      tile[ty + i][tx] = f2bf(((const float*)s)[(long)(c0 + ty + i) * HW + n0 + tx]);
    else
      tile[ty + i][tx] = ((const u16*)s)[(long)(c0 + ty + i) * HW + n0 + tx];
  }
  __syncthreads();
#pragma unroll
  for (int i = 0; i < 32; i += 8)
    d[(long)(n0 + ty + i) * 192 + c0 + tx] = tile[tx][ty + i];
}

// ---------------- main MFMA GEMM ----------------
// C[b][m][n] = sum_k A[m][k] * Bt[b][n][k], K = NSEG*192.
// For NSEG==9: segment s=(dy,dx) reads Bt row (n + dy*128 + dx), zero-page when
// the shifted pixel crosses the image border (pad=1 conv).
// Tile BM=64 x BN=256 x BK=32; 4 waves as 2x2, each 32x128 (2x8 mfma tiles).
// LDS layout: 16B chunks grouped [16-row block][quad(k/8)][row%16] so that
// global_load_lds staging (lane*16 contiguous) and ds_read_b128 frag loads
// (16 consecutive rows, fixed quad) are both conflict-free.
template <int NSEG, bool OUT_BF16>
__global__ __launch_bounds__(256, 2) void gemm_kernel(
    const u16* __restrict__ A, const u16* __restrict__ Bt,
    void* __restrict__ Cout, const u16* __restrict__ zp,
    int M, long aBatchStride) {
  __shared__ __align__(16) u16 shA[2048];   // 64 rows x 32 bf16
  __shared__ __align__(16) u16 shB[8192];   // 256 rows x 32 bf16
  const int Ktot = NSEG * 192;
  const int tid = threadIdx.x;
  const int w = tid >> 6;
  const int lane = tid & 63;
  const int rl = lane & 15;
  const int q4 = lane >> 4;
  const int wm = w & 1, wn = w >> 1;
  const int b = blockIdx.z;
  const int n0 = blockIdx.x * 256;
  const int m0 = blockIdx.y * 64;

  const u16* Ab = A + (long)b * aBatchStride + (long)m0 * Ktot;
  const u16* Btb = Bt + (long)b * HW * 192;
  const char* asrc = (const char*)(Ab + (long)(w * 16 + rl) * Ktot) + q4 * 16;

  f32x4 acc[2][8];
#pragma unroll
  for (int i = 0; i < 2; ++i)
#pragma unroll
    for (int j = 0; j < 8; ++j) acc[i][j] = f32x4{0.f, 0.f, 0.f, 0.f};

  const int lane_off = (q4 * 16 + rl) * 8;  // frag-read offset within a 16-row block

  for (int seg = 0; seg < NSEG; ++seg) {
    const char* bsrc[4];
    if constexpr (NSEG == 1) {
#pragma unroll
      for (int j = 0; j < 4; ++j) {
        int n = n0 + (w * 4 + j) * 16 + rl;
        bsrc[j] = (const char*)(Btb + (long)n * 192) + q4 * 16;
      }
    } else {
      int dy = seg / 3 - 1, dx = seg % 3 - 1;
#pragma unroll
      for (int j = 0; j < 4; ++j) {
        int n = n0 + (w * 4 + j) * 16 + rl;
        int xx = n & 127, yy = n >> 7;
        bool ok = ((unsigned)(xx + dx) < 128u) && ((unsigned)(yy + dy) < 128u);
        bsrc[j] = ok ? (const char*)(Btb + (long)(n + dy * 128 + dx) * 192) + q4 * 16
                     : (const char*)zp + q4 * 16;  // zp is 512B of zeros
      }
    }
    const int acol = seg * 192;
#pragma unroll
    for (int kk = 0; kk < 192; kk += 32) {
      g2l16(asrc + (long)(acol + kk) * 2, &shA[w * 512]);
#pragma unroll
      for (int j = 0; j < 4; ++j)
        g2l16(bsrc[j] + (long)kk * 2, &shB[(w * 4 + j) * 512]);
      __syncthreads();
      bf16x8 af[2], bfr[8];
#pragma unroll
      for (int i = 0; i < 2; ++i)
        af[i] = *(const bf16x8*)&shA[(wm * 32 + i * 16) * 32 + lane_off];
#pragma unroll
      for (int j = 0; j < 8; ++j)
        bfr[j] = *(const bf16x8*)&shB[(wn * 128 + j * 16) * 32 + lane_off];
#pragma unroll
      for (int i = 0; i < 2; ++i)
#pragma unroll
        for (int j = 0; j < 8; ++j)
          acc[i][j] = __builtin_amdgcn_mfma_f32_16x16x32_bf16(af[i], bfr[j], acc[i][j], 0, 0, 0);
      __syncthreads();
    }
  }
  // epilogue: D row = quad*4+reg (m), col = lane&15 (n)   [m89/m91 mapping]
  const int mb = m0 + wm * 32;
  const int nb = n0 + wn * 128;
  if (OUT_BF16) {
    u16* Cb = (u16*)Cout + (long)b * M * HW;
#pragma unroll
    for (int i = 0; i < 2; ++i)
#pragma unroll
      for (int j = 0; j < 8; ++j)
#pragma unroll
        for (int r = 0; r < 4; ++r)
          Cb[(long)(mb + i * 16 + q4 * 4 + r) * HW + nb + j * 16 + rl] = f2bf(acc[i][j][r]);
  } else {
    float* Cb = (float*)Cout + (long)b * M * HW;
#pragma unroll
    for (int i = 0; i < 2; ++i)
#pragma unroll
      for (int j = 0; j < 8; ++j)
#pragma unroll
        for (int r = 0; r < 4; ++r)
          Cb[(long)(mb + i * 16 + q4 * 4 + r) * HW + nb + j * 16 + rl] = acc[i][j][r];
  }
}

// ---------------- depthwise 3x3, pad 1 ----------------
// one block per (plane c, batch b); whole 128x128 bf16 plane staged in LDS.
__global__ __launch_bounds__(256) void dwconv_kernel(
    const u16* __restrict__ kv, const float* __restrict__ dww,
    u16* __restrict__ dst, int cbase, int dstCstride) {
  __shared__ __align__(16) u16 sp[HW];
  const int c = blockIdx.x;       // 0..191
  const int b = blockIdx.y;       // 0..7
  const int c2 = cbase + c;       // channel in kv (0..383)
  const u16* src = kv + ((long)b * 384 + c2) * HW;
  u16* out = dst + ((long)b * dstCstride + c) * HW;
  const int tid = threadIdx.x;
#pragma unroll
  for (int it = 0; it < 8; ++it)
    ((u16x8*)sp)[it * 256 + tid] = ((const u16x8*)src)[it * 256 + tid];
  __syncthreads();
  float w9[9];
#pragma unroll
  for (int t = 0; t < 9; ++t) w9[t] = dww[c2 * 9 + t];
  for (int o = 0; o < 8; ++o) {
    const int base = o * 2048 + tid * 8;   // 8 consecutive x pixels
    const int yy = base >> 7;
    const int x0 = base & 127;             // multiple of 8
    float vv[3][10];
#pragma unroll
    for (int r = 0; r < 3; ++r) {
      int yr = yy + r - 1;
      if (yr >= 0 && yr < 128) {
        const u16* rp = sp + yr * 128 + x0;
        u16x8 mid = *(const u16x8*)rp;
#pragma unroll
        for (int i2 = 0; i2 < 8; ++i2) vv[r][1 + i2] = bf2f(mid[i2]);
        vv[r][0] = (x0 > 0)   ? bf2f(rp[-1]) : 0.f;
        vv[r][9] = (x0 < 120) ? bf2f(rp[8])  : 0.f;
      } else {
#pragma unroll
        for (int i2 = 0; i2 < 10; ++i2) vv[r][i2] = 0.f;
      }
    }
    u16x8 ov;
#pragma unroll
    for (int i2 = 0; i2 < 8; ++i2) {
      float s = 0.f;
#pragma unroll
      for (int r = 0; r < 3; ++r)
#pragma unroll
        for (int d = 0; d < 3; ++d) s += w9[r * 3 + d] * vv[r][i2 + d];
      ov[i2] = f2bf(s);
    }
    *(u16x8*)(out + base) = ov;
  }
}

// ---------------- reciprocal L2 row norms over HW ----------------
__global__ __launch_bounds__(256) void rownorm_kernel(
    const u16* __restrict__ src, float* __restrict__ rnorm) {
  __shared__ float wsum[4];
  const long row = blockIdx.x;
  const int tid = threadIdx.x;
  const u16x8* p = (const u16x8*)(src + row * HW);
  float s = 0.f;
#pragma unroll
  for (int it = 0; it < 8; ++it) {
    u16x8 v = p[it * 256 + tid];
#pragma unroll
    for (int i = 0; i < 8; ++i) { float f = bf2f(v[i]); s += f * f; }
  }
#pragma unroll
  for (int off = 32; off; off >>= 1) s += __shfl_down(s, off, 64);
  if ((tid & 63) == 0) wsum[tid >> 6] = s;
  __syncthreads();
  if (tid == 0)
    rnorm[row] = 1.0f / fmaxf(sqrtf(wsum[0] + wsum[1] + wsum[2] + wsum[3]), 1e-12f);
}

// ---------------- Gram: gram[b,h][cl][dl] = sum_hw q[cl]*k[dl] ----------------
// one block per (b,h); 4 waves split K=16384; MFMA frags loaded straight from
// global (48x16384 bf16 slices are L2-resident); LDS reduction of partials.
__global__ __launch_bounds__(256) void gram_kernel(
    const u16* __restrict__ qq, const u16* __restrict__ kk, float* __restrict__ gram) {
  __shared__ float red[4 * 2304];
  const int bh = blockIdx.x;             // 0..31
  const int b = bh >> 2, h = bh & 3;
  const u16* qb = qq + ((long)b * 192 + h * 48) * HW;
  const u16* kb = kk + ((long)b * 192 + h * 48) * HW;
  const int tid = threadIdx.x, w = tid >> 6, lane = tid & 63;
  const int rl = lane & 15, q4 = lane >> 4;
  f32x4 acc[3][3];
#pragma unroll
  for (int i = 0; i < 3; ++i)
#pragma unroll
    for (int j = 0; j < 3; ++j) acc[i][j] = f32x4{0.f, 0.f, 0.f, 0.f};
  for (int t = 0; t < 128; ++t) {
    const int k0 = (t * 4 + w) * 32 + q4 * 8;
    bf16x8 af[3], bfr[3];
#pragma unroll
    for (int i = 0; i < 3; ++i) af[i] = *(const bf16x8*)(qb + (long)(i * 16 + rl) * HW + k0);
#pragma unroll
    for (int j = 0; j < 3; ++j) bfr[j] = *(const bf16x8*)(kb + (long)(j * 16 + rl) * HW + k0);
#pragma unroll
    for (int i = 0; i < 3; ++i)
#pragma unroll
      for (int j = 0; j < 3; ++j)
        acc[i][j] = __builtin_amdgcn_mfma_f32_16x16x32_bf16(af[i], bfr[j], acc[i][j], 0, 0, 0);
  }
#pragma unroll
  for (int i = 0; i < 3; ++i)
#pragma unroll
    for (int j = 0; j < 3; ++j)
#pragma unroll
      for (int r = 0; r < 4; ++r)
        red[w * 2304 + (i * 16 + q4 * 4 + r) * 48 + j * 16 + rl] = acc[i][j][r];
  __syncthreads();
  for (int e = tid; e < 2304; e += 256)
    gram[(long)bh * 2304 + e] = red[e] + red[2304 + e] + red[4608 + e] + red[6912 + e];
}

// ---------------- softmax over dl (one wave per (b,h,cl) row) ----------------
__global__ __launch_bounds__(64) void softmax_kernel(
    const float* __restrict__ gram, const float* __restrict__ rq,
    const float* __restrict__ rk, const float* __restrict__ temperature,
    float* __restrict__ attn) {
  const int R = blockIdx.x;            // b*192 + h*48 + cl
  const int lane = threadIdx.x;
  const int b = R / 192;
  const int h = (R % 192) / 48;
  const float ts = temperature[h] * 3.8712010109078907f;  // ln(48)
  float val = -3.0e38f;
  if (lane < 48)
    val = gram[(long)R * 48 + lane] * rq[R] * rk[b * 192 + h * 48 + lane] * ts;
  float mx = val;
#pragma unroll
  for (int off = 32; off; off >>= 1) mx = fmaxf(mx, __shfl_xor(mx, off, 64));
  float ex = (lane < 48) ? expf(val - mx) : 0.f;
  float sm = ex;
#pragma unroll
  for (int off = 32; off; off >>= 1) sm += __shfl_xor(sm, off, 64);
  if (lane < 48) attn[(long)R * 48 + lane] = ex / sm;
}

// ---------------- PA[b][o][dg] = sum_cl proj[o][hg*48+cl] * attn[b,hg,cl,dl] ----
__global__ __launch_bounds__(192) void pa_kernel(
    const float* __restrict__ proj_w, const float* __restrict__ attn,
    u16* __restrict__ PA) {
  const int b = blockIdx.x;     // 0..7
  const int o = blockIdx.y;     // 0..191
  const int dg = threadIdx.x;   // 0..191
  const int hg = dg / 48, dl = dg % 48;
  const float* arow = attn + ((long)(b * 4 + hg) * 48) * 48 + dl;
  const float* prow = proj_w + o * 192 + hg * 48;
  float s = 0.f;
#pragma unroll
  for (int cl = 0; cl < 48; ++cl) s += prow[cl] * arow[(long)cl * 48];
  PA[((long)b * 192 + o) * 192 + dg] = f2bf(s);
}

// ---------------- launch ----------------
extern "C" void kernel_launch(void* const* d_in, const int* in_sizes, int n_in,
                              void* d_out, int out_size, void* d_ws, size_t ws_size,
                              hipStream_t stream) {
  (void)in_sizes; (void)n_in; (void)out_size; (void)ws_size;
  const float* x        = (const float*)d_in[0];
  const float* y        = (const float*)d_in[1];
  const float* kv_w     = (const float*)d_in[2];
  const float* kv_dw_w  = (const float*)d_in[3];
  const float* q_w      = (const float*)d_in[4];
  const float* q_dw_w   = (const float*)d_in[5];
  const float* proj_w   = (const float*)d_in[6];
  const float* temperature = (const float*)d_in[7];

  char* ws = (char*)d_ws;
  u16* KV = (u16*)(ws + 0L);           // 100,663,296 B : kv[8][384][HW]; later v interleaved
  u16* R0 = (u16*)(ws + 100663296L);   // 50,331,648 B  : yT -> k
  u16* R1 = (u16*)(ws + 150994944L);   // 50,331,648 B  : q1 -> qq
  u16* R2 = (u16*)(ws + 201326592L);   // 50,331,648 B  : q1T -> xT -> vT
  char* tail = ws + 251658240L;        // ~2 MiB tail
  u16*   W1   = (u16*)(tail);
  u16*   W2   = (u16*)(tail + 147456);
  u16*   W3   = (u16*)(tail + 221184);
  u16*   PA   = (u16*)(tail + 884736);
  float* rq   = (float*)(tail + 1474560);
  float* rk   = (float*)(tail + 1480704);
  float* gram = (float*)(tail + 1486848);
  float* attn = (float*)(tail + 1781760);
  u16*   zp   = (u16*)(tail + 2076672);  // 512 B zero page

  hipMemsetAsync(zp, 0, 512, stream);
  pack_weights<<<1728, 256, 0, stream>>>(kv_w, q_w, q_dw_w, W1, W2, W3);

  // ---- q path ----
  transpose_kernel<float><<<dim3(512, 6, 8), 256, 0, stream>>>(y, R0, 192);        // yT
  gemm_kernel<1, true><<<dim3(64, 3, 8), 256, 0, stream>>>(W2, R0, R1, zp, 192, 0);  // q1
  transpose_kernel<u16><<<dim3(512, 6, 8), 256, 0, stream>>>(R1, R2, 192);          // q1T
  gemm_kernel<9, true><<<dim3(64, 3, 8), 256, 0, stream>>>(W3, R2, R1, zp, 192, 0);  // q (3x3)
  rownorm_kernel<<<1536, 256, 0, stream>>>(R1, rq);

  // ---- kv path ----
  transpose_kernel<float><<<dim3(512, 6, 8), 256, 0, stream>>>(x, R2, 192);         // xT
  gemm_kernel<1, true><<<dim3(64, 6, 8), 256, 0, stream>>>(W1, R2, KV, zp, 384, 0);  // kv
  dwconv_kernel<<<dim3(192, 8), 256, 0, stream>>>(KV, kv_dw_w, R0, 0, 192);          // k
  dwconv_kernel<<<dim3(192, 8), 256, 0, stream>>>(KV, kv_dw_w, KV, 192, 384);        // v (into dead k-half)
  transpose_kernel<u16><<<dim3(512, 6, 8), 256, 0, stream>>>(KV, R2, 384);           // vT
  rownorm_kernel<<<1536, 256, 0, stream>>>(R0, rk);

  // ---- attention + projection ----
  gram_kernel<<<32, 256, 0, stream>>>(R1, R0, gram);
  softmax_kernel<<<1536, 64, 0, stream>>>(gram, rq, rk, temperature, attn);
  pa_kernel<<<dim3(8, 192), 192, 0, stream>>>(proj_w, attn, PA);
  gemm_kernel<1, false><<<dim3(64, 3, 8), 256, 0, stream>>>(PA, R2, d_out, zp, 192, 36864);
}

// Round 2
// 673.520 us; speedup vs baseline: 1.1728x; 1.1728x over previous
//
#include <hip/hip_runtime.h>

// MDTA attention, B=8 C=192 H=W=128 heads=4 (ch=48), all-bf16 MFMA pipeline.
// R2: q path folded: W4[o][seg*192+c] = sum_ic q_dw_w[o][ic][seg]*q_w[ic][c],
//     so q = NSEG9-GEMM(W4, yT) directly (q1 stage deleted).
//     GEMM BK=64 (32 MFMA per barrier pair), fused rq/rk sumsq, split-K gram.

#define HW 16384

using f32x4  = __attribute__((ext_vector_type(4))) float;
using bf16x8 = __attribute__((ext_vector_type(8))) __bf16;
using u16x8  = __attribute__((ext_vector_type(8))) unsigned short;
typedef unsigned short u16;

__device__ __forceinline__ u16 f2bf(float f) {
  unsigned u = __builtin_bit_cast(unsigned, f);
  u = (u + 0x7fffu + ((u >> 16) & 1u)) >> 16;   // RNE
  return (u16)u;
}
__device__ __forceinline__ float bf2f(u16 s) {
  unsigned u = ((unsigned)s) << 16;
  return __builtin_bit_cast(float, u);
}

// async global->LDS, 16B/lane; LDS dest is wave-uniform base + lane*16
__device__ __forceinline__ void g2l16(const void* g, void* l) {
  __builtin_amdgcn_global_load_lds(
      (const __attribute__((address_space(1))) unsigned int*)g,
      (__attribute__((address_space(3))) unsigned int*)l, 16, 0, 0);
}

// ---------------- W1 pack: kv_w [384][192] fp32 -> bf16 ----------------
__global__ __launch_bounds__(256) void pack_w1(
    const float* __restrict__ kv_w, u16* __restrict__ W1) {
  int i = blockIdx.x * 256 + threadIdx.x;
  W1[i] = f2bf(kv_w[i]);
}

// ---------------- W4[o][seg*192+c] = sum_ic q_dw_w[(o*192+ic)*9+seg]*q_w[ic*192+c]
__global__ __launch_bounds__(192) void make_w4(
    const float* __restrict__ q_w, const float* __restrict__ q_dw_w,
    u16* __restrict__ W4) {
  const int o = blockIdx.x / 9, seg = blockIdx.x % 9;
  const int c = threadIdx.x;
  float s = 0.f;
  for (int ic = 0; ic < 192; ++ic)
    s += q_dw_w[(o * 192 + ic) * 9 + seg] * q_w[ic * 192 + c];
  W4[o * 1728 + seg * 192 + c] = f2bf(s);
}

// ---------------- transpose [b][C][HW] -> [b][HW][192] bf16 ----------------
template <typename TIn>
__global__ __launch_bounds__(256) void transpose_kernel(
    const TIn* __restrict__ src, u16* __restrict__ dst, int srcCstride) {
  __shared__ u16 tile[32][34];
  const int bz = blockIdx.z;
  const int n0 = blockIdx.x * 32;
  const int c0 = blockIdx.y * 32;
  const TIn* s = src + (long)bz * srcCstride * HW;
  u16* d = dst + (long)bz * HW * 192;
  const int tx = threadIdx.x & 31;
  const int ty = threadIdx.x >> 5;
#pragma unroll
  for (int i = 0; i < 32; i += 8) {
    if constexpr (sizeof(TIn) == 4)
      tile[ty + i][tx] = f2bf(((const float*)s)[(long)(c0 + ty + i) * HW + n0 + tx]);
    else
      tile[ty + i][tx] = ((const u16*)s)[(long)(c0 + ty + i) * HW + n0 + tx];
  }
  __syncthreads();
#pragma unroll
  for (int i = 0; i < 32; i += 8)
    d[(long)(n0 + ty + i) * 192 + c0 + tx] = tile[tx][ty + i];
}

// ---------------- main MFMA GEMM, BK=64 ----------------
// C[b][m][n] = sum_k A[m][k] * Bt[b][n][k], K = NSEG*192.
// NSEG==9: segment s=(dy,dx) reads Bt row (n + dy*128 + dx), zero page at borders.
// Tile 64x256x64; 4 waves 2x2, each 32x128. LDS slot = staging lane index, so
// frag read addr = base + lane*16 (conflict-free) and staging is the identity.
template <int NSEG, bool OUT_BF16, bool FUSE_RQ>
__global__ __launch_bounds__(256, 3) void gemm_kernel(
    const u16* __restrict__ A, const u16* __restrict__ Bt,
    void* __restrict__ Cout, const u16* __restrict__ zp,
    int M, long aBatchStride, float* __restrict__ rqs) {
  __shared__ __align__(16) u16 shA[4096];    // 64 rows x 64 k
  __shared__ __align__(16) u16 shB[16384];   // 256 rows x 64 k
  const int Ktot = NSEG * 192;
  const int tid = threadIdx.x;
  const int w = tid >> 6;
  const int lane = tid & 63;
  const int rl = lane & 15;
  const int q4 = lane >> 4;
  const int wm = w & 1, wn = w >> 1;
  const int b = blockIdx.z;
  const int n0 = blockIdx.x * 256;
  const int m0 = blockIdx.y * 64;

  const u16* Ab = A + (long)b * aBatchStride + (long)m0 * Ktot;
  const u16* Btb = Bt + (long)b * HW * 192;
  const char* asrc = (const char*)(Ab + (long)(w * 16 + rl) * Ktot) + q4 * 16;

  f32x4 acc[2][8];
#pragma unroll
  for (int i = 0; i < 2; ++i)
#pragma unroll
    for (int j = 0; j < 8; ++j) acc[i][j] = f32x4{0.f, 0.f, 0.f, 0.f};

  const int lane_off = lane * 8;   // u16 offset of this lane's frag slot

  for (int seg = 0; seg < NSEG; ++seg) {
    const char* bsrc[4];
    if constexpr (NSEG == 1) {
#pragma unroll
      for (int j = 0; j < 4; ++j) {
        int n = n0 + (w * 4 + j) * 16 + rl;
        bsrc[j] = (const char*)(Btb + (long)n * 192) + q4 * 16;
      }
    } else {
      int dy = seg / 3 - 1, dx = seg % 3 - 1;
#pragma unroll
      for (int j = 0; j < 4; ++j) {
        int n = n0 + (w * 4 + j) * 16 + rl;
        int xx = n & 127, yy = n >> 7;
        bool ok = ((unsigned)(xx + dx) < 128u) && ((unsigned)(yy + dy) < 128u);
        bsrc[j] = ok ? (const char*)(Btb + (long)(n + dy * 128 + dx) * 192) + q4 * 16
                     : (const char*)zp + q4 * 16;
      }
    }
    const long acol = (long)seg * 192;
#pragma unroll
    for (int kk = 0; kk < 192; kk += 64) {
      const long ao = (acol + kk) * 2;
      g2l16(asrc + ao, &shA[w * 1024]);
      g2l16(asrc + ao + 64, &shA[w * 1024 + 512]);
#pragma unroll
      for (int j = 0; j < 4; ++j) {
        g2l16(bsrc[j] + kk * 2, &shB[(w * 4 + j) * 1024]);
        g2l16(bsrc[j] + kk * 2 + 64, &shB[(w * 4 + j) * 1024 + 512]);
      }
      __syncthreads();
      bf16x8 af[2][2];
#pragma unroll
      for (int i = 0; i < 2; ++i)
#pragma unroll
        for (int h = 0; h < 2; ++h)
          af[i][h] = *(const bf16x8*)&shA[(wm * 2 + i) * 1024 + h * 512 + lane_off];
#pragma unroll
      for (int jh = 0; jh < 2; ++jh) {
        bf16x8 bfr[4][2];
#pragma unroll
        for (int j2 = 0; j2 < 4; ++j2)
#pragma unroll
          for (int h = 0; h < 2; ++h)
            bfr[j2][h] = *(const bf16x8*)&shB[(wn * 8 + jh * 4 + j2) * 1024 + h * 512 + lane_off];
#pragma unroll
        for (int i = 0; i < 2; ++i)
#pragma unroll
          for (int j2 = 0; j2 < 4; ++j2) {
            const int j = jh * 4 + j2;
            acc[i][j] = __builtin_amdgcn_mfma_f32_16x16x32_bf16(af[i][0], bfr[j2][0], acc[i][j], 0, 0, 0);
            acc[i][j] = __builtin_amdgcn_mfma_f32_16x16x32_bf16(af[i][1], bfr[j2][1], acc[i][j], 0, 0, 0);
          }
      }
      __syncthreads();
    }
  }
  // epilogue: D row m = quad*4+reg, col n = lane&15  [m89/m91 mapping]
  const int mb = m0 + wm * 32;
  const int nb = n0 + wn * 128;
  if constexpr (OUT_BF16) {
    u16* Cb = (u16*)Cout + (long)b * M * HW;
#pragma unroll
    for (int i = 0; i < 2; ++i)
#pragma unroll
      for (int j = 0; j < 8; ++j)
#pragma unroll
        for (int r = 0; r < 4; ++r)
          Cb[(long)(mb + i * 16 + q4 * 4 + r) * HW + nb + j * 16 + rl] = f2bf(acc[i][j][r]);
  } else {
    float* Cb = (float*)Cout + (long)b * M * HW;
#pragma unroll
    for (int i = 0; i < 2; ++i)
#pragma unroll
      for (int j = 0; j < 8; ++j)
#pragma unroll
        for (int r = 0; r < 4; ++r)
          Cb[(long)(mb + i * 16 + q4 * 4 + r) * HW + nb + j * 16 + rl] = acc[i][j][r];
  }
  if constexpr (FUSE_RQ) {
    // per-row sum of squares over this block's 256-col slice -> atomicAdd
#pragma unroll
    for (int i = 0; i < 2; ++i)
#pragma unroll
      for (int r = 0; r < 4; ++r) {
        float s = 0.f;
#pragma unroll
        for (int j = 0; j < 8; ++j) s += acc[i][j][r] * acc[i][j][r];
        s += __shfl_xor(s, 1, 64);
        s += __shfl_xor(s, 2, 64);
        s += __shfl_xor(s, 4, 64);
        s += __shfl_xor(s, 8, 64);
        if (rl == 0)
          atomicAdd(&rqs[b * 192 + mb + i * 16 + q4 * 4 + r], s);
      }
  }
}

// ---------------- depthwise 3x3, pad 1 (optional fused sumsq) ----------------
template <bool FUSE_NORM>
__global__ __launch_bounds__(256) void dwconv_kernel(
    const u16* __restrict__ kv, const float* __restrict__ dww,
    u16* __restrict__ dst, int cbase, int dstCstride, float* __restrict__ rks) {
  __shared__ __align__(16) u16 sp[HW];
  const int c = blockIdx.x;       // 0..191
  const int b = blockIdx.y;       // 0..7
  const int c2 = cbase + c;       // channel in kv (0..383)
  const u16* src = kv + ((long)b * 384 + c2) * HW;
  u16* out = dst + ((long)b * dstCstride + c) * HW;
  const int tid = threadIdx.x;
#pragma unroll
  for (int it = 0; it < 8; ++it)
    ((u16x8*)sp)[it * 256 + tid] = ((const u16x8*)src)[it * 256 + tid];
  __syncthreads();
  float w9[9];
#pragma unroll
  for (int t = 0; t < 9; ++t) w9[t] = dww[c2 * 9 + t];
  float ssum = 0.f;
  for (int o = 0; o < 8; ++o) {
    const int base = o * 2048 + tid * 8;
    const int yy = base >> 7;
    const int x0 = base & 127;
    float vv[3][10];
#pragma unroll
    for (int r = 0; r < 3; ++r) {
      int yr = yy + r - 1;
      if (yr >= 0 && yr < 128) {
        const u16* rp = sp + yr * 128 + x0;
        u16x8 mid = *(const u16x8*)rp;
#pragma unroll
        for (int i2 = 0; i2 < 8; ++i2) vv[r][1 + i2] = bf2f(mid[i2]);
        vv[r][0] = (x0 > 0)   ? bf2f(rp[-1]) : 0.f;
        vv[r][9] = (x0 < 120) ? bf2f(rp[8])  : 0.f;
      } else {
#pragma unroll
        for (int i2 = 0; i2 < 10; ++i2) vv[r][i2] = 0.f;
      }
    }
    u16x8 ov;
#pragma unroll
    for (int i2 = 0; i2 < 8; ++i2) {
      float s = 0.f;
#pragma unroll
      for (int r = 0; r < 3; ++r)
#pragma unroll
        for (int d = 0; d < 3; ++d) s += w9[r * 3 + d] * vv[r][i2 + d];
      if constexpr (FUSE_NORM) ssum += s * s;
      ov[i2] = f2bf(s);
    }
    *(u16x8*)(out + base) = ov;
  }
  if constexpr (FUSE_NORM) {
#pragma unroll
    for (int off = 32; off; off >>= 1) ssum += __shfl_down(ssum, off, 64);
    if ((tid & 63) == 0) atomicAdd(&rks[b * 192 + c], ssum);
  }
}

// ---------------- Gram, split-K: 32 (b,h) x 8 k-chunks, atomicAdd ----------------
__global__ __launch_bounds__(256) void gram_kernel(
    const u16* __restrict__ qq, const u16* __restrict__ kk, float* __restrict__ gram) {
  __shared__ float red[4 * 2304];
  const int bh = blockIdx.x;             // 0..31
  const int kc = blockIdx.y;             // 0..7
  const int b = bh >> 2, h = bh & 3;
  const u16* qb = qq + ((long)b * 192 + h * 48) * HW;
  const u16* kb = kk + ((long)b * 192 + h * 48) * HW;
  const int tid = threadIdx.x, w = tid >> 6, lane = tid & 63;
  const int rl = lane & 15, q4 = lane >> 4;
  f32x4 acc[3][3];
#pragma unroll
  for (int i = 0; i < 3; ++i)
#pragma unroll
    for (int j = 0; j < 3; ++j) acc[i][j] = f32x4{0.f, 0.f, 0.f, 0.f};
  for (int tt = 0; tt < 16; ++tt) {
    const int k0 = ((kc * 16 + tt) * 4 + w) * 32 + q4 * 8;
    bf16x8 af[3], bfr[3];
#pragma unroll
    for (int i = 0; i < 3; ++i) af[i] = *(const bf16x8*)(qb + (long)(i * 16 + rl) * HW + k0);
#pragma unroll
    for (int j = 0; j < 3; ++j) bfr[j] = *(const bf16x8*)(kb + (long)(j * 16 + rl) * HW + k0);
#pragma unroll
    for (int i = 0; i < 3; ++i)
#pragma unroll
      for (int j = 0; j < 3; ++j)
        acc[i][j] = __builtin_amdgcn_mfma_f32_16x16x32_bf16(af[i], bfr[j], acc[i][j], 0, 0, 0);
  }
#pragma unroll
  for (int i = 0; i < 3; ++i)
#pragma unroll
    for (int j = 0; j < 3; ++j)
#pragma unroll
      for (int r = 0; r < 4; ++r)
        red[w * 2304 + (i * 16 + q4 * 4 + r) * 48 + j * 16 + rl] = acc[i][j][r];
  __syncthreads();
  for (int e = tid; e < 2304; e += 256)
    atomicAdd(&gram[(long)bh * 2304 + e], red[e] + red[2304 + e] + red[4608 + e] + red[6912 + e]);
}

// ---------------- softmax over dl (one wave per (b,h,cl) row) ----------------
__global__ __launch_bounds__(64) void softmax_kernel(
    const float* __restrict__ gram, const float* __restrict__ rqs,
    const float* __restrict__ rks, const float* __restrict__ temperature,
    float* __restrict__ attn) {
  const int R = blockIdx.x;            // b*192 + h*48 + cl
  const int lane = threadIdx.x;
  const int b = R / 192;
  const int h = (R % 192) / 48;
  const float ts = temperature[h] * 3.8712010109078907f;  // ln(48)
  const float rq = rsqrtf(fmaxf(rqs[R], 1e-24f));
  float val = -3.0e38f;
  if (lane < 48) {
    const float rk = rsqrtf(fmaxf(rks[b * 192 + h * 48 + lane], 1e-24f));
    val = gram[(long)R * 48 + lane] * rq * rk * ts;
  }
  float mx = val;
#pragma unroll
  for (int off = 32; off; off >>= 1) mx = fmaxf(mx, __shfl_xor(mx, off, 64));
  float ex = (lane < 48) ? expf(val - mx) : 0.f;
  float sm = ex;
#pragma unroll
  for (int off = 32; off; off >>= 1) sm += __shfl_xor(sm, off, 64);
  if (lane < 48) attn[(long)R * 48 + lane] = ex / sm;
}

// ---------------- PA[b][o][dg] = sum_cl proj[o][hg*48+cl] * attn[b,hg,cl,dl] ----
__global__ __launch_bounds__(192) void pa_kernel(
    const float* __restrict__ proj_w, const float* __restrict__ attn,
    u16* __restrict__ PA) {
  const int b = blockIdx.x;     // 0..7
  const int o = blockIdx.y;     // 0..191
  const int dg = threadIdx.x;   // 0..191
  const int hg = dg / 48, dl = dg % 48;
  const float* arow = attn + ((long)(b * 4 + hg) * 48) * 48 + dl;
  const float* prow = proj_w + o * 192 + hg * 48;
  float s = 0.f;
#pragma unroll
  for (int cl = 0; cl < 48; ++cl) s += prow[cl] * arow[(long)cl * 48];
  PA[((long)b * 192 + o) * 192 + dg] = f2bf(s);
}

// ---------------- launch ----------------
extern "C" void kernel_launch(void* const* d_in, const int* in_sizes, int n_in,
                              void* d_out, int out_size, void* d_ws, size_t ws_size,
                              hipStream_t stream) {
  (void)in_sizes; (void)n_in; (void)out_size; (void)ws_size;
  const float* x        = (const float*)d_in[0];
  const float* y        = (const float*)d_in[1];
  const float* kv_w     = (const float*)d_in[2];
  const float* kv_dw_w  = (const float*)d_in[3];
  const float* q_w      = (const float*)d_in[4];
  const float* q_dw_w   = (const float*)d_in[5];
  const float* proj_w   = (const float*)d_in[6];
  const float* temperature = (const float*)d_in[7];

  char* ws = (char*)d_ws;
  u16* KV = (u16*)(ws + 0L);           // kv[8][384][HW]; later v into ch 0..191
  u16* R0 = (u16*)(ws + 100663296L);   // k [8][192][HW]
  u16* R1 = (u16*)(ws + 150994944L);   // q [8][192][HW]
  u16* R2 = (u16*)(ws + 201326592L);   // yT -> xT -> vT [8][HW][192]
  char* tail = ws + 251658240L;
  u16*   zp   = (u16*)(tail + 0);        // 512 B zeros
  float* rqs  = (float*)(tail + 512);    // 6144 B
  float* rks  = (float*)(tail + 6656);   // 6144 B
  float* gram = (float*)(tail + 12800);  // 294912 B
  float* attn = (float*)(tail + 307712); // 294912 B
  u16*   W1   = (u16*)(tail + 602624);   // 147456 B
  u16*   W4   = (u16*)(tail + 750080);   // 663552 B
  u16*   PA   = (u16*)(tail + 1413632);  // 589824 B

  hipMemsetAsync(tail, 0, 307712, stream);   // zp + rqs + rks + gram
  pack_w1<<<288, 256, 0, stream>>>(kv_w, W1);
  make_w4<<<1728, 192, 0, stream>>>(q_w, q_dw_w, W4);

  // ---- q path: yT -> q (3x3 merged) with fused rq ----
  transpose_kernel<float><<<dim3(512, 6, 8), 256, 0, stream>>>(y, R2, 192);
  gemm_kernel<9, true, true><<<dim3(64, 3, 8), 256, 0, stream>>>(W4, R2, R1, zp, 192, 0, rqs);

  // ---- kv path ----
  transpose_kernel<float><<<dim3(512, 6, 8), 256, 0, stream>>>(x, R2, 192);
  gemm_kernel<1, true, false><<<dim3(64, 6, 8), 256, 0, stream>>>(W1, R2, KV, zp, 384, 0, nullptr);
  dwconv_kernel<true><<<dim3(192, 8), 256, 0, stream>>>(KV, kv_dw_w, R0, 0, 192, rks);
  dwconv_kernel<false><<<dim3(192, 8), 256, 0, stream>>>(KV, kv_dw_w, KV, 192, 384, nullptr);
  transpose_kernel<u16><<<dim3(512, 6, 8), 256, 0, stream>>>(KV, R2, 384);

  // ---- attention + projection ----
  gram_kernel<<<dim3(32, 8), 256, 0, stream>>>(R1, R0, gram);
  softmax_kernel<<<1536, 64, 0, stream>>>(gram, rqs, rks, temperature, attn);
  pa_kernel<<<dim3(8, 192), 192, 0, stream>>>(proj_w, attn, PA);
  gemm_kernel<1, false, false><<<dim3(64, 3, 8), 256, 0, stream>>>(PA, R2, d_out, zp, 192, 36864, nullptr);
}